// Round 1
// 109.865 us; speedup vs baseline: 1.0464x; 1.0464x over previous
//
#include <hip/hip_runtime.h>
#include <stdint.h>

#define B_ 64
#define S_ 512
#define EMB_ 256
#define NIN_ 7
#define NOUT_ 4
#define HID_ 512
#define VOCAB_ 1000
#define VP_ 1024          // vocab padded to 1024 rows
#define NG_ 2048          // table cols: [fwd z/f interleaved 1024 | bwd 1024]
#define M_ (B_ * S_)

typedef __bf16 bf16x8 __attribute__((ext_vector_type(8)));
typedef float floatx4 __attribute__((ext_vector_type(4)));
typedef unsigned short u16x8 __attribute__((ext_vector_type(8)));

__device__ __forceinline__ unsigned short f2bf(float f) {
    unsigned u = __float_as_uint(f);
    u += 0x7FFFu + ((u >> 16) & 1u);   // RNE
    return (unsigned short)(u >> 16);
}
__device__ __forceinline__ float bf2f(unsigned short h) {
    return __uint_as_float(((unsigned)h) << 16);
}
__device__ __forceinline__ float rcp_(float x) { return __builtin_amdgcn_rcpf(x); }
// raw v_exp_f32: computes 2^x (single trans op; fold log2e into the operand)
__device__ __forceinline__ float exp2_(float x) {
    float r; asm("v_exp_f32 %0, %1" : "=v"(r) : "v"(x)); return r;
}
#define L2E_ 1.4426950408889634f
__device__ __forceinline__ float sigmoidf_(float x) {
    return rcp_(1.0f + exp2_(x * (-L2E_)));
}
__device__ __forceinline__ float tanhf_(float x) {
    float ax = fabsf(x);
    float e = exp2_(ax * (-2.0f * L2E_));
    float t = (1.0f - e) * rcp_(1.0f + e);
    return copysignf(t, x);
}

// virtual table col v (0..2047): part = v>>10 (0 fwd Wf, 1 bwd Wb),
// m = v&1023, j = m>>1, zf = m&1, source col c = zf ? 512+j : j.
// G[row][2j] = z-gate, G[row][2j+1] = f-gate (fwd); +1024 for bwd.
// MFMA fragment-order chunks: chunk = ((g>>3)*8 + kt)*8 + (g&7), 512 shorts;
// lane entry (16*kchunk + v15)*8 holds 8 bf16 at k = kt*32 + kchunk*8 + q.
//
// NOTE (R6 post-mortem, prior session): do NOT fuse final_out into scan via
// device-scope fences — ~130 µs of writeback serialization across XCD L2s.
//
// R1 this session: (a) WT built via coalesced row reads + LDS transpose
// (was: stride-6KB scalar gathers, ~8 lines/inst, latency-bound);
// (b) W7(7x2048) -> W4(4x2048) with per-token n4 = num@Wn computed once per
// block in scan (14 FMA + 7 LDS reads/step -> 8 FMA + 1 uniform b128 read);
// (c) 2-deep G prefetch in scan; (d) exp2-folded activations;
// (e) shfl reduction in final_out.

// ---------------- K1: prep: Aemb frags, WT frags, W4/bvec -------------------
__global__ __launch_bounds__(256) void prep(
    const float* __restrict__ emb, const float* __restrict__ bn,
    const float* __restrict__ Wf, const float* __restrict__ bfv,
    const float* __restrict__ Wb, const float* __restrict__ bb,
    unsigned short* __restrict__ Aemb, unsigned short* __restrict__ WT,
    float* __restrict__ W4, float* __restrict__ bvec) {
    int bid = blockIdx.x;
    int tid = threadIdx.x;

    if (bid < 64) {                         // ---- Aemb: rows 16*bid..+15
        int g = bid;
#pragma unroll
        for (int half = 0; half < 2; ++half) {
            int t = tid + 256 * half;
            int r15 = t & 15;
            int kchunk = (t >> 4) & 3;
            int kt = t >> 6;                // 0..7
            int row = g * 16 + r15;
            int k0 = kt * 32 + kchunk * 8;
            unsigned short p[8];
            if (row < VOCAB_) {
                float4 a = *(const float4*)(emb + (size_t)row * EMB_ + k0);
                float4 b = *(const float4*)(emb + (size_t)row * EMB_ + k0 + 4);
                p[0]=f2bf(a.x); p[1]=f2bf(a.y); p[2]=f2bf(a.z); p[3]=f2bf(a.w);
                p[4]=f2bf(b.x); p[5]=f2bf(b.y); p[6]=f2bf(b.z); p[7]=f2bf(b.w);
            } else {
#pragma unroll
                for (int q = 0; q < 8; ++q) p[q] = 0;
            }
            size_t chunk = ((size_t)(g >> 3) * 8 + kt) * 8 + (g & 7);
            *(u16x8*)(Aemb + chunk * 512 + (16 * kchunk + r15) * 8) =
                *(const u16x8*)p;
        }
    } else if (bid < 80) {                  // ---- WT via coalesced read + LDS transpose
        __shared__ float raw[32][132];      // 32 k-rows x 128 cols (pad 132)
        int idx = bid - 64;                 // 0..15
        int p = idx >> 3;                   // part: 0 fwd, 1 bwd
        int gq = idx & 7;                   // col-stripe: j0 = gq*64
        const float* W = p ? Wb : Wf;
        int j0 = gq * 64;
        int r = tid >> 3;                   // 0..31 (k-row within tile)
        int i = tid & 7;                    // 0..7  (8 threads per row)

#pragma unroll
        for (int kt = 0; kt < 8; ++kt) {
            int k0 = kt * 32;
            const float* src = W + (size_t)(k0 + r) * 1536;
            // stripe A: z-gate cols j0..j0+63; stripe B: f-gate cols 512+j0..+63
            float4 a0 = *(const float4*)(src + j0 + i * 8);
            float4 a1 = *(const float4*)(src + j0 + i * 8 + 4);
            float4 b0 = *(const float4*)(src + 512 + j0 + i * 8);
            float4 b1 = *(const float4*)(src + 512 + j0 + i * 8 + 4);
            *(float4*)&raw[r][i * 8]      = a0;
            *(float4*)&raw[r][i * 8 + 4]  = a1;
            *(float4*)&raw[r][64 + i * 8]     = b0;
            *(float4*)&raw[r][64 + i * 8 + 4] = b1;
            __syncthreads();
#pragma unroll
            for (int h = 0; h < 2; ++h) {
                int e = tid + 256 * h;      // 0..511 fragment entries
                int gl = e >> 6;            // 0..7 local group
                int rest = e & 63;
                int kchunk = rest >> 4;
                int v15 = rest & 15;
                int joff = gl * 8 + (v15 >> 1);       // 0..63
                int cl = joff + 64 * (v15 & 1);       // LDS col
                unsigned short pk[8];
#pragma unroll
                for (int q = 0; q < 8; ++q) pk[q] = f2bf(raw[kchunk * 8 + q][cl]);
                int g = p * 64 + gq * 8 + gl;
                size_t chunk = ((size_t)(g >> 3) * 8 + kt) * 8 + (g & 7);
                *(u16x8*)(WT + chunk * 512 + (16 * kchunk + v15) * 8) =
                    *(const u16x8*)pk;
            }
            __syncthreads();
        }
    } else {                                // ---- W4 (4 x 2048) + bvec (2048)
        int v = (bid - 80) * 256 + tid;     // bid 80..87
        int part = v >> 10;
        int m = v & 1023;
        int j = m >> 1;
        int c = (m & 1) ? (512 + j) : j;
        const float* W = part ? Wb : Wf;
        float bv = part ? bb[c] : bfv[c];
#pragma unroll
        for (int q = 0; q < NOUT_; ++q) {
            float w = W[(size_t)(256 + q) * 1536 + c];
            W4[(size_t)q * NG_ + v] = w;
            bv = fmaf(bn[q], w, bv);
        }
        bvec[v] = bv;
    }
}

// ---------------- K2: G = Aemb @ WT + bvec (1024 x 2048, K=256) -------------
// barrier-free register-double-buffered K-loop.
__global__ __launch_bounds__(256) void gemmG(
    const unsigned short* __restrict__ Aemb, const unsigned short* __restrict__ WT,
    const float* __restrict__ bvec, unsigned short* __restrict__ G) {
    int bid = blockIdx.x;                   // 128 = 8 mtiles x 16 ntiles
    int mtile = bid & 7;
    int ntile = bid >> 3;
    int r0 = mtile * 128;
    int n0 = ntile * 128;
    int tid = threadIdx.x;
    int lane = tid & 63, wave = tid >> 6;
    int wm = wave & 1, wn = wave >> 1;
    int rl = lane & 15;

    const unsigned short* pa = Aemb + ((size_t)mtile * 64 + 4 * wm) * 512 + lane * 8;
    const unsigned short* pb = WT + ((size_t)ntile * 64 + 4 * wn) * 512 + lane * 8;

    floatx4 acc[4][4];
#pragma unroll
    for (int mi = 0; mi < 4; ++mi)
#pragma unroll
        for (int ni = 0; ni < 4; ++ni) acc[mi][ni] = (floatx4){0.f, 0.f, 0.f, 0.f};

    bf16x8 afc[4], bfc[4], afn[4], bfn[4];
#pragma unroll
    for (int mi = 0; mi < 4; ++mi) afc[mi] = *(const bf16x8*)(pa + mi * 512);
#pragma unroll
    for (int ni = 0; ni < 4; ++ni) bfc[ni] = *(const bf16x8*)(pb + ni * 512);

#pragma unroll
    for (int kt = 0; kt < 8; ++kt) {
        if (kt < 7) {
#pragma unroll
            for (int mi = 0; mi < 4; ++mi)
                afn[mi] = *(const bf16x8*)(pa + (size_t)(kt + 1) * 4096 + mi * 512);
#pragma unroll
            for (int ni = 0; ni < 4; ++ni)
                bfn[ni] = *(const bf16x8*)(pb + (size_t)(kt + 1) * 4096 + ni * 512);
        }
#pragma unroll
        for (int mi = 0; mi < 4; ++mi)
#pragma unroll
            for (int ni = 0; ni < 4; ++ni)
                acc[mi][ni] = __builtin_amdgcn_mfma_f32_16x16x32_bf16(afc[mi], bfc[ni], acc[mi][ni], 0, 0, 0);
        if (kt < 7) {
#pragma unroll
            for (int mi = 0; mi < 4; ++mi) afc[mi] = afn[mi];
#pragma unroll
            for (int ni = 0; ni < 4; ++ni) bfc[ni] = bfn[ni];
        }
    }

    // C/D: col = lane&15, row = (lane>>4)*4 + reg  [m89/m91]
#pragma unroll
    for (int ni = 0; ni < 4; ++ni) {
        int n = n0 + 64 * wn + 16 * ni + rl;
        float bv = bvec[n];
#pragma unroll
        for (int mi = 0; mi < 4; ++mi) {
            int rb = r0 + 64 * wm + 16 * mi + (lane >> 4) * 4;
#pragma unroll
            for (int v = 0; v < 4; ++v)
                G[(size_t)(rb + v) * NG_ + n] = f2bf(acc[mi][ni][v] + bv);
        }
    }
}

// ---------------- K3: gather-scan: 512 blocks (b x 8 chunks) x 512 thr ------
__global__ __launch_bounds__(512) void scan(
    const float* __restrict__ X, const unsigned short* __restrict__ G,
    const float* __restrict__ W4, const float* __restrict__ Wn,
    float* __restrict__ PQ) {
    __shared__ float LX[512];               // 64 steps x 8 floats
    __shared__ float LN[64][4];             // per-token n4 = num @ Wn
    int bid = blockIdx.x;
    int b = bid >> 3, chunk = bid & 7;
    int s0 = chunk * 64;
    int j = threadIdx.x;                    // chain 0..511

    LX[j] = X[((size_t)b * S_ + s0 + (j >> 3)) * 8 + (j & 7)];
    __syncthreads();

    if (j < 256) {                          // token t = j>>2, output q = j&3
        int t = j >> 2, q = j & 3;
        float s = 0.f;
#pragma unroll
        for (int i = 0; i < NIN_; ++i) s = fmaf(LX[t * 8 + 1 + i], Wn[i * NOUT_ + q], s);
        LN[t][q] = s;
    }

    float2 w4p[NOUT_];
#pragma unroll
    for (int q = 0; q < NOUT_; ++q)
        w4p[q] = *(const float2*)(W4 + (size_t)q * NG_ + 2 * j);
    __syncthreads();

    float P = 1.f, Q = 0.f;
    int ev0 = (int)LX[0];
    unsigned gpA = *(const unsigned*)(G + (size_t)ev0 * NG_ + 2 * j);
    int ev1 = (int)LX[8];
    unsigned gpB = *(const unsigned*)(G + (size_t)ev1 * NG_ + 2 * j);
#pragma unroll 4
    for (int s = 0; s < 64; ++s) {
        unsigned gpc = gpA;
        gpA = gpB;
        if (s < 62) {                       // 2-deep prefetch
            int evn = (int)LX[(s + 2) * 8];
            gpB = *(const unsigned*)(G + (size_t)evn * NG_ + 2 * j);
        }
        float gz = bf2f((unsigned short)(gpc & 0xffffu));
        float gf = bf2f((unsigned short)(gpc >> 16));
        float4 n4 = *(const float4*)(&LN[s][0]);    // uniform b128 broadcast
        gz = fmaf(n4.x, w4p[0].x, gz);
        gz = fmaf(n4.y, w4p[1].x, gz);
        gz = fmaf(n4.z, w4p[2].x, gz);
        gz = fmaf(n4.w, w4p[3].x, gz);
        gf = fmaf(n4.x, w4p[0].y, gf);
        gf = fmaf(n4.y, w4p[1].y, gf);
        gf = fmaf(n4.z, w4p[2].y, gf);
        gf = fmaf(n4.w, w4p[3].y, gf);
        float z = tanhf_(gz);
        float f = sigmoidf_(gf);
        Q = fmaf(f, Q - z, z);              // f*Q + (1-f)*z
        P *= f;
    }
    ((float2*)PQ)[(size_t)bid * 512 + j] = make_float2(P, Q);
}

// ---------------- K4: fold chunks + backward (1 step) + Wo dot --------------
__global__ __launch_bounds__(512) void final_out(
    const float* __restrict__ X, const unsigned short* __restrict__ G,
    const float* __restrict__ W4, const float* __restrict__ Wn,
    const float* __restrict__ Wo, const float* __restrict__ bo,
    const float* __restrict__ PQ, float* __restrict__ out) {
    int b = blockIdx.x;
    int j = threadIdx.x;                    // 0..511

    float h = 0.f;
#pragma unroll
    for (int c = 0; c < 8; ++c) {
        float2 pq = ((const float2*)PQ)[((size_t)b * 8 + c) * 512 + j];
        h = fmaf(pq.x, h, pq.y);
    }

    const float* xr = X + ((size_t)b * S_ + (S_ - 1)) * 8;
    int ev = (int)xr[0];
    float n4[NOUT_];
#pragma unroll
    for (int q = 0; q < NOUT_; ++q) {
        float s = 0.f;
#pragma unroll
        for (int i = 0; i < NIN_; ++i) s = fmaf(xr[1 + i], Wn[i * NOUT_ + q], s);
        n4[q] = s;
    }
    unsigned gpc = *(const unsigned*)(G + (size_t)ev * NG_ + 1024 + 2 * j);
    float gz = bf2f((unsigned short)(gpc & 0xffffu));
    float gf = bf2f((unsigned short)(gpc >> 16));
#pragma unroll
    for (int q = 0; q < NOUT_; ++q) {
        float2 w = *(const float2*)(W4 + (size_t)q * NG_ + 1024 + 2 * j);
        gz = fmaf(n4[q], w.x, gz);
        gf = fmaf(n4[q], w.y, gf);
    }
    float hb = (1.f - sigmoidf_(gf)) * tanhf_(gz);

    float partial = fmaf(h, Wo[j], hb * Wo[512 + j]);
#pragma unroll
    for (int off = 32; off > 0; off >>= 1)
        partial += __shfl_down(partial, off);
    __shared__ float red[8];
    if ((j & 63) == 0) red[j >> 6] = partial;
    __syncthreads();
    if (j == 0) {
        float s = bo[0];
#pragma unroll
        for (int w = 0; w < 8; ++w) s += red[w];
        out[b] = s;
    }
}

extern "C" void kernel_launch(void* const* d_in, const int* in_sizes, int n_in,
                              void* d_out, int out_size, void* d_ws, size_t ws_size,
                              hipStream_t stream) {
    const float* X   = (const float*)d_in[0];
    const float* emb = (const float*)d_in[1];
    const float* Wn  = (const float*)d_in[2];
    const float* bn  = (const float*)d_in[3];
    const float* Wf  = (const float*)d_in[4];
    const float* bfv = (const float*)d_in[5];
    const float* Wb  = (const float*)d_in[6];
    const float* bb  = (const float*)d_in[7];
    const float* Wo  = (const float*)d_in[8];
    const float* bo  = (const float*)d_in[9];
    float* out = (float*)d_out;

    size_t off_A  = 0;
    size_t off_WT = off_A  + (size_t)VP_ * EMB_ * 2;          // 512 KB
    size_t off_G  = off_WT + (size_t)NG_ * EMB_ * 2;          // +1 MB
    size_t off_W4 = off_G  + (size_t)VP_ * NG_ * 2;           // +4 MB
    size_t off_bv = off_W4 + (size_t)NOUT_ * NG_ * 4;         // +32 KB
    size_t off_PQ = off_bv + (size_t)NG_ * 4;                 // +8 KB
    size_t need   = off_PQ + (size_t)B_ * 8 * 512 * 2 * sizeof(float);  // +2 MB
    if (ws_size < need) return;

    unsigned short* Aemb = (unsigned short*)((char*)d_ws + off_A);
    unsigned short* WT   = (unsigned short*)((char*)d_ws + off_WT);
    unsigned short* G    = (unsigned short*)((char*)d_ws + off_G);
    float*          W4   = (float*)((char*)d_ws + off_W4);
    float*          bvec = (float*)((char*)d_ws + off_bv);
    float*          PQ   = (float*)((char*)d_ws + off_PQ);

    prep<<<88, 256, 0, stream>>>(emb, bn, Wf, bfv, Wb, bb, Aemb, WT, W4, bvec);
    gemmG<<<128, 256, 0, stream>>>(Aemb, WT, bvec, G);
    scan<<<512, 512, 0, stream>>>(X, G, W4, Wn, PQ);
    final_out<<<64, 512, 0, stream>>>(X, G, W4, Wn, Wo, bo, PQ, out);
}